// Round 5
// baseline (4648.254 us; speedup 1.0000x reference)
//
#include <hip/hip_runtime.h>
#include <hip/hip_bf16.h>

// LSTM: L=512 steps, N=64 batch, I=H=1024.
// Round 10: FULL-K WAVES + LANE-LOCAL GATES on the proven round-5 protocol.
//  - 128 WGs x 512 thr (8 waves = 2 col-halves x 4 batch-quarters). Each wave
//    owns a 16x16 z-tile (4 gates x 4 cols x 16 batches) with FULL K=1024:
//    C-layout (col=lane&15, row=quad*4+reg) puts the 4 gates of one
//    (col,batch) in one lane's 4 acc regs -> gates lane-local, NO LDS reduce,
//    NO __syncthreads in the loop (removes 2 barriers + 1.7e7 bank conflicts).
//  - W_hh frags register-resident (128 VGPR). W_ih in LDS (64 KB, frag-
//    swizzled at prologue) feeds the x-half.
//  - x-half(t+1) computed off the critical path into fresh 4-way accs that
//    CARRY IN REGISTERS into step t+1's h-half (no zx buffer; ws = round-5's
//    proven ~131 MB layout).
//  - Publish = round-5 proven: sc1 store -> drain -> flag; drain overlapped
//    with x-load issue via exact in-order vmcnt counting (store is oldest).
//  - Flags [1024]: idx = nh*256 + mt*128 + wg. Consumer polls its
//    batch-quarter's 256 flags (4 wave-wide loads).
// Fallback (ws too small): round-5 parity+flags kernel, verbatim.
// Packed slab layout [64 x 1024]: elem(row,col) -> idx (col>>3)*512 + row*8 + (col&7)

#define L_STEPS 512
#define NB 64
#define HID 1024
#define SLOT 65536              // elems per packed slab/slot (128 KB)

typedef __bf16 bf16x8 __attribute__((ext_vector_type(8)));
typedef __bf16 bf16x2 __attribute__((ext_vector_type(2)));
typedef float  f32x4  __attribute__((ext_vector_type(4)));
typedef float  f32x2  __attribute__((ext_vector_type(2)));
typedef unsigned u32x4 __attribute__((ext_vector_type(4)));

__device__ __forceinline__ float sigmoid_f(float x) {
    return 1.f / (1.f + __expf(-x));
}
__device__ __forceinline__ float tanh_f(float x) {
    return 1.f - 2.f / (1.f + __expf(2.f * x));
}

__global__ void convert_kernel(const float* __restrict__ x, const float* __restrict__ h0,
                               __bf16* __restrict__ xbf, __bf16* __restrict__ hbf,
                               unsigned* __restrict__ bar) {
    unsigned u = blockIdx.x * 256u + threadIdx.x;
    if (u < 1024u) bar[u] = 0u;
    const int row = u & 63;
    const int cg  = (u >> 6) & 127;
    if (u < 8192u) {   // h0 -> packed slot 0
        const float* s = h0 + (size_t)row * HID + cg * 8;
        f32x4 a = *(const f32x4*)s, b = *(const f32x4*)(s + 4);
        bf16x8 o;
        o[0]=(__bf16)a[0]; o[1]=(__bf16)a[1]; o[2]=(__bf16)a[2]; o[3]=(__bf16)a[3];
        o[4]=(__bf16)b[0]; o[5]=(__bf16)b[1]; o[6]=(__bf16)b[2]; o[7]=(__bf16)b[3];
        ((bf16x8*)hbf)[u] = o;
    }
    const int t = u >> 13;
    const float* s = x + ((size_t)t * NB + row) * HID + cg * 8;
    f32x4 a = *(const f32x4*)s, b = *(const f32x4*)(s + 4);
    bf16x8 o;
    o[0]=(__bf16)a[0]; o[1]=(__bf16)a[1]; o[2]=(__bf16)a[2]; o[3]=(__bf16)a[3];
    o[4]=(__bf16)b[0]; o[5]=(__bf16)b[1]; o[6]=(__bf16)b[2]; o[7]=(__bf16)b[3];
    ((bf16x8*)xbf)[u] = o;
}

// ============================ NEW PATH =====================================
// MFMA helpers: 4-way split accumulator chains (za..zd), chain = k&3.
#define MFH(K, IDX) do {                                                        \
    f32x4& d_ = ((K)&3)==0 ? za : ((K)&3)==1 ? zb : ((K)&3)==2 ? zc : zd;       \
    d_ = __builtin_amdgcn_mfma_f32_16x16x32_bf16(                               \
        wfh[(K)], __builtin_bit_cast(bf16x8, hb[(IDX)]), d_, 0, 0, 0);          \
} while (0)

#define MFX(K, IDX) do {                                                        \
    bf16x8 af_ = *(const bf16x8*)(&wih_lds[mt][(K)][lane][0]);                  \
    f32x4& d_ = ((K)&3)==0 ? za : ((K)&3)==1 ? zb : ((K)&3)==2 ? zc : zd;       \
    d_ = __builtin_amdgcn_mfma_f32_16x16x32_bf16(                               \
        af_, __builtin_bit_cast(bf16x8, hb[(IDX)]), d_, 0, 0, 0);               \
} while (0)

__global__ __launch_bounds__(512, 1) void lstm_fullk(
    const float* __restrict__ c0p,
    const float* __restrict__ W_ih, const float* __restrict__ W_hh,
    const float* __restrict__ b_ih, const float* __restrict__ b_hh,
    const __bf16* __restrict__ xbf,      // [512] packed 64x1024 slabs
    __bf16* hbuf,                        // ring: [513] slots, write-once
    unsigned* bar,                       // [1024]: idx = nh*256 + mt*128 + wg
    float* __restrict__ out)             // d_out: y[65536], h[65536], c[65536]
{
    const int tid  = threadIdx.x;
    const int lane = tid & 63;
    const int w8   = tid >> 6;
    const int nh   = w8 & 3;             // batch quarter
    const int mt   = w8 >> 2;            // col half
    const int quad = lane >> 4;
    const int l15  = lane & 15;
    const int wg   = blockIdx.x;
    const int hbase = wg * 8;

    const int col   = hbase + mt * 4 + quad;
    const int batch = nh * 16 + l15;

    // W_ih fragments in LDS: [mt][kk][lane][8 bf16] = 64 KB, frag-swizzled so
    // each lane's ds_read_b128 is its A-frag (consecutive lanes -> consecutive
    // 16B: conflict-free b128 pattern).
    __shared__ __bf16 wih_lds[2][32][64][8];
    for (int f = tid; f < 4096; f += 512) {
        const int fmt = f >> 11, fkk = (f >> 6) & 31, fl = f & 63;
        const int fl15 = fl & 15, fq = fl >> 4;
        const int wrow = (fl15 & 3) * HID + hbase + fmt * 4 + (fl15 >> 2);
        const float* src = W_ih + (size_t)wrow * HID + fkk * 32 + fq * 8;
        f32x4 a = *(const f32x4*)src, b = *(const f32x4*)(src + 4);
        bf16x8 fr;
        fr[0]=(__bf16)a[0]; fr[1]=(__bf16)a[1]; fr[2]=(__bf16)a[2]; fr[3]=(__bf16)a[3];
        fr[4]=(__bf16)b[0]; fr[5]=(__bf16)b[1]; fr[6]=(__bf16)b[2]; fr[7]=(__bf16)b[3];
        *(bf16x8*)&wih_lds[fmt][fkk][fl][0] = fr;
    }

    // ---- W_hh fragment preload (32 x bf16x8 = 128 VGPR). A-row n of the
    // wave's 16x16 tile -> W row (gate = n&3)*HID + hbase + mt*4 + (n>>2);
    // lane holds row n = l15, k-chunk = quad*8.
    bf16x8 wfh[32];
    {
        const int wrow = (l15 & 3) * HID + hbase + mt * 4 + (l15 >> 2);
        const float* wr = W_hh + (size_t)wrow * HID + quad * 8;
        #pragma unroll
        for (int kk = 0; kk < 32; ++kk) {
            const float* src = wr + kk * 32;
            f32x4 a = *(const f32x4*)src, b = *(const f32x4*)(src + 4);
            bf16x8 fr;
            fr[0]=(__bf16)a[0]; fr[1]=(__bf16)a[1]; fr[2]=(__bf16)a[2]; fr[3]=(__bf16)a[3];
            fr[4]=(__bf16)b[0]; fr[5]=(__bf16)b[1]; fr[6]=(__bf16)b[2]; fr[7]=(__bf16)b[3];
            wfh[kk] = fr;
        }
    }

    // per-lane bias (4 gates of this col) and cell state (1 per lane)
    f32x4 bias;
    #pragma unroll
    for (int g = 0; g < 4; ++g)
        bias[g] = b_ih[g * HID + col] + b_hh[g * HID + col];
    float cv = c0p[batch * HID + col];

    // offsets
    const int bOff  = quad * 512 + nh * 128 + l15 * 8;          // B-frag elems
    const int hsOff = wg * 512 + batch * 8 + mt * 4 + quad;     // h-store elems
    const int fpost = nh * 256 + mt * 128 + wg;
    const int pbase = nh * 256 + lane;

    __syncthreads();   // wih_lds ready (drains lgkm+vm before barrier)

    u32x4 hb[16];
    f32x4 za, zb, zc, zd;
    const f32x4 fzero = {0.f, 0.f, 0.f, 0.f};

    // ---- prologue: x partials for t=0 (acc = bias + x(0)@W_ih^T)
    asm volatile("s_waitcnt vmcnt(0)" ::: "memory");   // align vmcnt bookkeeping
    za = bias; zb = fzero; zc = fzero; zd = fzero;
    {
        const __bf16* xp = xbf + bOff;   // slab 0
        #pragma unroll
        for (int k = 0; k < 16; ++k)
            asm volatile("global_load_dwordx4 %0, %1, off" : "=v"(hb[k]) : "v"(xp + k * 2048));
        asm volatile("s_waitcnt vmcnt(8)"
            : "+v"(hb[0]), "+v"(hb[1]), "+v"(hb[2]), "+v"(hb[3]),
              "+v"(hb[4]), "+v"(hb[5]), "+v"(hb[6]), "+v"(hb[7]));
        #pragma unroll
        for (int k = 0; k < 8; ++k) MFX(k, k);
        #pragma unroll
        for (int k = 0; k < 8; ++k)
            asm volatile("global_load_dwordx4 %0, %1, off" : "=v"(hb[k]) : "v"(xp + (16 + k) * 2048));
        asm volatile("s_waitcnt vmcnt(8)"
            : "+v"(hb[8]), "+v"(hb[9]), "+v"(hb[10]), "+v"(hb[11]),
              "+v"(hb[12]), "+v"(hb[13]), "+v"(hb[14]), "+v"(hb[15]));
        #pragma unroll
        for (int k = 8; k < 16; ++k) MFX(k, k);
        #pragma unroll
        for (int k = 0; k < 8; ++k)
            asm volatile("global_load_dwordx4 %0, %1, off" : "=v"(hb[8 + k]) : "v"(xp + (24 + k) * 2048));
        asm volatile("s_waitcnt vmcnt(8)"
            : "+v"(hb[0]), "+v"(hb[1]), "+v"(hb[2]), "+v"(hb[3]),
              "+v"(hb[4]), "+v"(hb[5]), "+v"(hb[6]), "+v"(hb[7]));
        #pragma unroll
        for (int k = 16; k < 24; ++k) MFX(k, k - 16);
        asm volatile("s_waitcnt vmcnt(0)"
            : "+v"(hb[8]), "+v"(hb[9]), "+v"(hb[10]), "+v"(hb[11]),
              "+v"(hb[12]), "+v"(hb[13]), "+v"(hb[14]), "+v"(hb[15]));
        #pragma unroll
        for (int k = 24; k < 32; ++k) MFX(k, k - 16);
    }

    for (int t = 0; t < L_STEPS; ++t) {
        // ---- poll this batch-quarter's 256 producer flags (relaxed, hot lines)
        for (;;) {
            unsigned f0 = __hip_atomic_load(&bar[pbase],       __ATOMIC_RELAXED, __HIP_MEMORY_SCOPE_AGENT);
            unsigned f1 = __hip_atomic_load(&bar[pbase + 64],  __ATOMIC_RELAXED, __HIP_MEMORY_SCOPE_AGENT);
            unsigned f2 = __hip_atomic_load(&bar[pbase + 128], __ATOMIC_RELAXED, __HIP_MEMORY_SCOPE_AGENT);
            unsigned f3 = __hip_atomic_load(&bar[pbase + 192], __ATOMIC_RELAXED, __HIP_MEMORY_SCOPE_AGENT);
            if (__all((f0 >= (unsigned)t) && (f1 >= (unsigned)t) &&
                      (f2 >= (unsigned)t) && (f3 >= (unsigned)t))) break;
            __builtin_amdgcn_s_sleep(1);
        }
        // poll values consumed -> 0 outstanding vm ops here (exact counting).

        // ---- h half: 32 B-frag loads (slot t), rolling window 16, full K
        {
            const __bf16* bp = hbuf + (size_t)t * SLOT + bOff;
            #pragma unroll
            for (int k = 0; k < 16; ++k)
                asm volatile("global_load_dwordx4 %0, %1, off" : "=v"(hb[k]) : "v"(bp + k * 2048));
            asm volatile("s_waitcnt vmcnt(8)"
                : "+v"(hb[0]), "+v"(hb[1]), "+v"(hb[2]), "+v"(hb[3]),
                  "+v"(hb[4]), "+v"(hb[5]), "+v"(hb[6]), "+v"(hb[7]));
            #pragma unroll
            for (int k = 0; k < 8; ++k) MFH(k, k);
            #pragma unroll
            for (int k = 0; k < 8; ++k)
                asm volatile("global_load_dwordx4 %0, %1, off" : "=v"(hb[k]) : "v"(bp + (16 + k) * 2048));
            asm volatile("s_waitcnt vmcnt(8)"
                : "+v"(hb[8]), "+v"(hb[9]), "+v"(hb[10]), "+v"(hb[11]),
                  "+v"(hb[12]), "+v"(hb[13]), "+v"(hb[14]), "+v"(hb[15]));
            #pragma unroll
            for (int k = 8; k < 16; ++k) MFH(k, k);
            #pragma unroll
            for (int k = 0; k < 8; ++k)
                asm volatile("global_load_dwordx4 %0, %1, off" : "=v"(hb[8 + k]) : "v"(bp + (24 + k) * 2048));
            asm volatile("s_waitcnt vmcnt(8)"
                : "+v"(hb[0]), "+v"(hb[1]), "+v"(hb[2]), "+v"(hb[3]),
                  "+v"(hb[4]), "+v"(hb[5]), "+v"(hb[6]), "+v"(hb[7]));
            #pragma unroll
            for (int k = 16; k < 24; ++k) MFH(k, k - 16);
            asm volatile("s_waitcnt vmcnt(0)"
                : "+v"(hb[8]), "+v"(hb[9]), "+v"(hb[10]), "+v"(hb[11]),
                  "+v"(hb[12]), "+v"(hb[13]), "+v"(hb[14]), "+v"(hb[15]));
            #pragma unroll
            for (int k = 24; k < 32; ++k) MFH(k, k - 16);
        }

        // ---- gates: fully lane-local (reg r = gate r of this (col,batch))
        f32x4 z = (za + zb) + (zc + zd);
        float ig = sigmoid_f(z[0]), fg = sigmoid_f(z[1]);
        float gg = tanh_f(z[2]),    og = sigmoid_f(z[3]);
        cv = fg * cv + ig * gg;
        float hv = og * tanh_f(cv);

        if (t < L_STEPS - 1) {
            // ---- publish (round-5 proven drain-before-flag, overlapped):
            // store(oldest) -> issue 16 x loads -> vmcnt(16) drains exactly
            // the store (in-order counting) -> flag -> counted x windows.
            __bf16 hb16v = (__bf16)hv;
            unsigned hbits = (unsigned)__builtin_bit_cast(unsigned short, hb16v);
            const __bf16* dst = hbuf + (size_t)(t + 1) * SLOT + hsOff;
            asm volatile("global_store_short %0, %1, off sc1"
                         :: "v"(dst), "v"(hbits) : "memory");
            const __bf16* xp = xbf + (size_t)(t + 1) * SLOT + bOff;
            #pragma unroll
            for (int k = 0; k < 16; ++k)
                asm volatile("global_load_dwordx4 %0, %1, off" : "=v"(hb[k]) : "v"(xp + k * 2048));
            asm volatile("s_waitcnt vmcnt(16)" ::: "memory");    // store acked
            if (lane == 0)
                __hip_atomic_store(&bar[fpost], (unsigned)(t + 1),
                                   __ATOMIC_RELAXED, __HIP_MEMORY_SCOPE_AGENT);

            // ---- x half for t+2's z: acc_next = bias + x(t+1)@W_ih^T.
            // Counter order after flag: L0..L15, F (<=17 outstanding).
            za = bias; zb = fzero; zc = fzero; zd = fzero;
            asm volatile("s_waitcnt vmcnt(9)"      // >=8 oldest retired: L0..7
                : "+v"(hb[0]), "+v"(hb[1]), "+v"(hb[2]), "+v"(hb[3]),
                  "+v"(hb[4]), "+v"(hb[5]), "+v"(hb[6]), "+v"(hb[7]));
            #pragma unroll
            for (int k = 0; k < 8; ++k) MFX(k, k);
            #pragma unroll
            for (int k = 0; k < 8; ++k)
                asm volatile("global_load_dwordx4 %0, %1, off" : "=v"(hb[k]) : "v"(xp + (16 + k) * 2048));
            asm volatile("s_waitcnt vmcnt(9)"      // L8..15 retired
                : "+v"(hb[8]), "+v"(hb[9]), "+v"(hb[10]), "+v"(hb[11]),
                  "+v"(hb[12]), "+v"(hb[13]), "+v"(hb[14]), "+v"(hb[15]));
            #pragma unroll
            for (int k = 8; k < 16; ++k) MFX(k, k);
            #pragma unroll
            for (int k = 0; k < 8; ++k)
                asm volatile("global_load_dwordx4 %0, %1, off" : "=v"(hb[8 + k]) : "v"(xp + (24 + k) * 2048));
            asm volatile("s_waitcnt vmcnt(8)"      // F + L16..23 retired
                : "+v"(hb[0]), "+v"(hb[1]), "+v"(hb[2]), "+v"(hb[3]),
                  "+v"(hb[4]), "+v"(hb[5]), "+v"(hb[6]), "+v"(hb[7]));
            #pragma unroll
            for (int k = 16; k < 24; ++k) MFX(k, k - 16);
            asm volatile("s_waitcnt vmcnt(0)"      // all drained (incl. flag)
                : "+v"(hb[8]), "+v"(hb[9]), "+v"(hb[10]), "+v"(hb[11]),
                  "+v"(hb[12]), "+v"(hb[13]), "+v"(hb[14]), "+v"(hb[15]));
            #pragma unroll
            for (int k = 24; k < 32; ++k) MFX(k, k - 16);
        } else {
            const int idx = batch * HID + col;
            out[65536 + idx]  = hv;
            out[131072 + idx] = cv;
        }
    }
}

// ====================== FALLBACK (round-5, verbatim) =======================
__device__ __forceinline__ void mfma_x(const __bf16* __restrict__ act,
                                       const bf16x8 (&wfr)[2][8],
                                       f32x4 (&acc)[2][4]) {
    #pragma unroll
    for (int kk = 0; kk < 8; ++kk) {
        bf16x8 bfr[4];
        #pragma unroll
        for (int nt = 0; nt < 4; ++nt)
            bfr[nt] = *(const bf16x8*)(act + kk * 2048 + nt * 128);
        #pragma unroll
        for (int mt = 0; mt < 2; ++mt)
            #pragma unroll
            for (int nt = 0; nt < 4; ++nt)
                acc[mt][nt] = __builtin_amdgcn_mfma_f32_16x16x32_bf16(
                    wfr[mt][kk], bfr[nt], acc[mt][nt], 0, 0, 0);
    }
}

template <bool RING>
__global__ __launch_bounds__(256, 1) void lstm_kernel(
    const float* __restrict__ c0,
    const float* __restrict__ W_ih, const float* __restrict__ W_hh,
    const float* __restrict__ b_ih, const float* __restrict__ b_hh,
    const __bf16* __restrict__ xbf,
    __bf16* hbuf,
    unsigned* bar,
    float* __restrict__ out)
{
    const int tid  = threadIdx.x;
    const int lane = tid & 63;
    const int w    = tid >> 6;
    const int quad = lane >> 4;
    const int l15  = lane & 15;
    const int hbase = blockIdx.x * 8;

    __shared__ float red[4][64][44];

    bf16x8 wfx[2][8], wfh[2][8];
    #pragma unroll
    for (int mt = 0; mt < 2; ++mt) {
        const int n    = mt * 16 + l15;
        const int grow = (n >> 3) * HID + hbase + (n & 7);
        #pragma unroll
        for (int kk = 0; kk < 8; ++kk) {
            const int kcol = w * 256 + kk * 32 + quad * 8;
            {
                const float* src = W_ih + (size_t)grow * 1024 + kcol;
                f32x4 a = *(const f32x4*)src;
                f32x4 b = *(const f32x4*)(src + 4);
                bf16x8 f;
                f[0]=(__bf16)a[0]; f[1]=(__bf16)a[1]; f[2]=(__bf16)a[2]; f[3]=(__bf16)a[3];
                f[4]=(__bf16)b[0]; f[5]=(__bf16)b[1]; f[6]=(__bf16)b[2]; f[7]=(__bf16)b[3];
                wfx[mt][kk] = f;
            }
            {
                const float* src = W_hh + (size_t)grow * 1024 + kcol;
                f32x4 a = *(const f32x4*)src;
                f32x4 b = *(const f32x4*)(src + 4);
                bf16x8 f;
                f[0]=(__bf16)a[0]; f[1]=(__bf16)a[1]; f[2]=(__bf16)a[2]; f[3]=(__bf16)a[3];
                f[4]=(__bf16)b[0]; f[5]=(__bf16)b[1]; f[6]=(__bf16)b[2]; f[7]=(__bf16)b[3];
                wfh[mt][kk] = f;
            }
        }
    }

    const int p0 = tid * 2;
    const int cb = p0 >> 3;
    const int cu = p0 & 7;
    float c0v = c0[cb * HID + hbase + cu];
    float c1v = c0[cb * HID + hbase + cu + 1];

    float bias0[4], bias1[4];
    #pragma unroll
    for (int gate = 0; gate < 4; ++gate) {
        int gr = gate * HID + hbase + cu;
        bias0[gate] = b_ih[gr] + b_hh[gr];
        bias1[gate] = b_ih[gr + 1] + b_hh[gr + 1];
    }

    const int lane_off = (32 * w + quad) * 512 + l15 * 8;
    const int hstore_off = blockIdx.x * 512 + cb * 8 + cu;

    f32x4 acc[2][4];
    #pragma unroll
    for (int mt = 0; mt < 2; ++mt)
        #pragma unroll
        for (int nt = 0; nt < 4; ++nt) { f32x4 z = {0.f,0.f,0.f,0.f}; acc[mt][nt] = z; }
    mfma_x(xbf + lane_off, wfx, acc);

    const int pf0 = 128 * w + lane;
    const int pf1 = 128 * w + 64 + lane;

    for (int t = 0; t < L_STEPS; ++t) {
        for (;;) {
            unsigned f0 = __hip_atomic_load(&bar[pf0], __ATOMIC_RELAXED,
                                            __HIP_MEMORY_SCOPE_AGENT);
            unsigned f1 = __hip_atomic_load(&bar[pf1], __ATOMIC_RELAXED,
                                            __HIP_MEMORY_SCOPE_AGENT);
            if (__all((f0 >= (unsigned)t) && (f1 >= (unsigned)t))) break;
            __builtin_amdgcn_s_sleep(1);
        }

        u32x4 hb[8][4];
        const __bf16* hb_base = hbuf
            + (size_t)(RING ? t : (t & 1)) * (NB * HID) + lane_off;
        #pragma unroll
        for (int kk = 0; kk < 8; ++kk)
            #pragma unroll
            for (int nt = 0; nt < 4; ++nt) {
                const __bf16* p = hb_base + kk * 2048 + nt * 128;
                if constexpr (RING)
                    asm volatile("global_load_dwordx4 %0, %1, off"
                                 : "=v"(hb[kk][nt]) : "v"(p));
                else
                    asm volatile("global_load_dwordx4 %0, %1, off sc1"
                                 : "=v"(hb[kk][nt]) : "v"(p));
            }
        asm volatile("s_waitcnt vmcnt(16)"
            : "+v"(hb[0][0]), "+v"(hb[0][1]), "+v"(hb[0][2]), "+v"(hb[0][3]),
              "+v"(hb[1][0]), "+v"(hb[1][1]), "+v"(hb[1][2]), "+v"(hb[1][3]),
              "+v"(hb[2][0]), "+v"(hb[2][1]), "+v"(hb[2][2]), "+v"(hb[2][3]),
              "+v"(hb[3][0]), "+v"(hb[3][1]), "+v"(hb[3][2]), "+v"(hb[3][3]));
        #pragma unroll
        for (int kk = 0; kk < 4; ++kk)
            #pragma unroll
            for (int mt = 0; mt < 2; ++mt)
                #pragma unroll
                for (int nt = 0; nt < 4; ++nt)
                    acc[mt][nt] = __builtin_amdgcn_mfma_f32_16x16x32_bf16(
                        wfh[mt][kk], __builtin_bit_cast(bf16x8, hb[kk][nt]),
                        acc[mt][nt], 0, 0, 0);
        asm volatile("s_waitcnt vmcnt(0)"
            : "+v"(hb[4][0]), "+v"(hb[4][1]), "+v"(hb[4][2]), "+v"(hb[4][3]),
              "+v"(hb[5][0]), "+v"(hb[5][1]), "+v"(hb[5][2]), "+v"(hb[5][3]),
              "+v"(hb[6][0]), "+v"(hb[6][1]), "+v"(hb[6][2]), "+v"(hb[6][3]),
              "+v"(hb[7][0]), "+v"(hb[7][1]), "+v"(hb[7][2]), "+v"(hb[7][3]));
        #pragma unroll
        for (int kk = 4; kk < 8; ++kk)
            #pragma unroll
            for (int mt = 0; mt < 2; ++mt)
                #pragma unroll
                for (int nt = 0; nt < 4; ++nt)
                    acc[mt][nt] = __builtin_amdgcn_mfma_f32_16x16x32_bf16(
                        wfh[mt][kk], __builtin_bit_cast(bf16x8, hb[kk][nt]),
                        acc[mt][nt], 0, 0, 0);

        __syncthreads();

        #pragma unroll
        for (int mt = 0; mt < 2; ++mt)
            #pragma unroll
            for (int nt = 0; nt < 4; ++nt) {
                const int row0 = mt * 16 + quad * 4;
                const int col  = nt * 16 + l15;
                *(f32x4*)&red[w][col][row0] = acc[mt][nt];
            }
        __syncthreads();

        float h0v, h1v;
        {
            float z0[4], z1[4];
            #pragma unroll
            for (int gate = 0; gate < 4; ++gate) {
                const int row = gate * 8 + cu;
                f32x2 s0 = *(const f32x2*)&red[0][cb][row];
                f32x2 s1 = *(const f32x2*)&red[1][cb][row];
                f32x2 s2 = *(const f32x2*)&red[2][cb][row];
                f32x2 s3 = *(const f32x2*)&red[3][cb][row];
                z0[gate] = s0[0] + s1[0] + s2[0] + s3[0] + bias0[gate];
                z1[gate] = s0[1] + s1[1] + s2[1] + s3[1] + bias1[gate];
            }
            float ig = sigmoid_f(z0[0]), fg = sigmoid_f(z0[1]);
            float gg = tanh_f(z0[2]),    og = sigmoid_f(z0[3]);
            c0v = fg * c0v + ig * gg;
            h0v = og * tanh_f(c0v);
            ig = sigmoid_f(z1[0]); fg = sigmoid_f(z1[1]);
            gg = tanh_f(z1[2]);    og = sigmoid_f(z1[3]);
            c1v = fg * c1v + ig * gg;
            h1v = og * tanh_f(c1v);
        }

        {
            bf16x2 hv; hv[0] = (__bf16)h0v; hv[1] = (__bf16)h1v;
            unsigned hbits = __builtin_bit_cast(unsigned, hv);
            const __bf16* dst = hbuf
                + (size_t)(RING ? (t + 1) : ((t + 1) & 1)) * (NB * HID) + hstore_off;
            asm volatile("global_store_dword %0, %1, off sc1"
                         :: "v"(dst), "v"(hbits) : "memory");
        }
        if (t == L_STEPS - 1) {
            const int idx = cb * HID + hbase + cu;
            out[65536 + idx]      = h0v;
            out[65536 + idx + 1]  = h1v;
            out[131072 + idx]     = c0v;
            out[131072 + idx + 1] = c1v;
        }
        asm volatile("s_waitcnt vmcnt(0)" ::: "memory");
        if (lane == 0)
            __hip_atomic_store(&bar[blockIdx.x * 4 + w], (unsigned)(t + 1),
                               __ATOMIC_RELAXED, __HIP_MEMORY_SCOPE_AGENT);

        #pragma unroll
        for (int mt = 0; mt < 2; ++mt)
            #pragma unroll
            for (int nt = 0; nt < 4; ++nt) { f32x4 z = {0.f,0.f,0.f,0.f}; acc[mt][nt] = z; }
        if (t < L_STEPS - 1)
            mfma_x(xbf + (size_t)(t + 1) * (NB * HID) + lane_off, wfx, acc);
    }
}

__global__ void out_kernel(const float* __restrict__ base, const float* __restrict__ Wout,
                           const float* __restrict__ bout, float* __restrict__ y)
{
    const int wv   = (int)((blockIdx.x * 256u + threadIdx.x) >> 6);
    const int lane = threadIdx.x & 63;
    const int b = wv >> 10;
    const int i = wv & 1023;
    const f32x4* hp = (const f32x4*)(base + 65536 + b * HID);
    const f32x4* wp = (const f32x4*)(Wout + (size_t)i * HID);
    float acc = 0.f;
    #pragma unroll
    for (int q = 0; q < 4; ++q) {
        f32x4 hv = hp[q * 64 + lane];
        f32x4 wvv = wp[q * 64 + lane];
        acc += hv[0]*wvv[0] + hv[1]*wvv[1] + hv[2]*wvv[2] + hv[3]*wvv[3];
    }
    #pragma unroll
    for (int off = 32; off > 0; off >>= 1) acc += __shfl_down(acc, off);
    if (lane == 0) y[b * HID + i] = acc + bout[i];
}

extern "C" void kernel_launch(void* const* d_in, const int* in_sizes, int n_in,
                              void* d_out, int out_size, void* d_ws, size_t ws_size,
                              hipStream_t stream)
{
    const float* x    = (const float*)d_in[0];
    const float* h0   = (const float*)d_in[1];
    const float* c0   = (const float*)d_in[2];
    const float* W_ih = (const float*)d_in[3];
    const float* W_hh = (const float*)d_in[4];
    const float* b_ih = (const float*)d_in[5];
    const float* b_hh = (const float*)d_in[6];
    const float* Wout = (const float*)d_in[7];
    const float* bout = (const float*)d_in[8];
    float* out = (float*)d_out;
    char* ws = (char*)d_ws;

    // ws layout: xbf (64 MB) | hbuf (ring: 513 slots = 64.1 MB, else 256 KB) | bar
    const size_t XBF_B  = 67108864;                  // 512 x 131072
    const size_t RING_B = 513ull * 131072;           // 67,239,936
    const size_t need_ring = XBF_B + RING_B + 4096;
    const bool ring = ws_size >= need_ring;

    __bf16* xbf   = (__bf16*)(ws);
    __bf16* hbuf  = (__bf16*)(ws + XBF_B);
    unsigned* bar = (unsigned*)(ws + XBF_B + (ring ? RING_B : 262144));

    convert_kernel<<<16384, 256, 0, stream>>>(x, h0, xbf, hbuf, bar);
    if (ring)
        lstm_fullk<<<128, 512, 0, stream>>>(c0, W_ih, W_hh, b_ih, b_hh,
                                            xbf, hbuf, bar, out);
    else
        lstm_kernel<false><<<128, 256, 0, stream>>>(c0, W_ih, W_hh, b_ih, b_hh,
                                                    xbf, hbuf, bar, out);
    out_kernel<<<16384, 256, 0, stream>>>(out, Wout, bout, out);
}